// Round 5
// baseline (97.549 us; speedup 1.0000x reference)
//
#include <hip/hip_runtime.h>

// FOFE windowed encoder via cross-window recurrence.
// out[b,c,j,t] = sum_{k<w_j} alpha^k x[t-1-k],  w_j = j (j=0..47), w_48 = 64.
// Recurrence over windows: out_{j+1}[t] = out_j[t] + alpha^j * x[t-1-j].
// Each lane keeps 4 output columns in REGISTERS across all windows; per step:
// 1 LDS read + 4 fmaf + 1 16B store. (R1 vs R3 showed store format is a
// non-lever; the 8-reads+swizzle-math per f32x4 was the serial cost.)

#define CC 512
#define LL 512
#define NW 49
#define LO 513
#define PAD 68    // front zeros: x[m]=0 for m<0, need m >= -65
#define XSZ 592

typedef float f32x4 __attribute__((ext_vector_type(4)));

// XOR-swizzle: stride-4 lane reads would hit 8 banks; inject idx bits [6:5]
// into bank bits [1:0] -> 2 lanes/bank (free, m136). Involution, bijective.
__device__ __forceinline__ int swz(int i) { return i ^ ((i >> 5) & 3); }

__global__ __launch_bounds__(256, 8)
void fofe_kernel(const float* __restrict__ x,
                 const float* __restrict__ alpha,
                 float* __restrict__ out)
{
    // 4 waves/block: waves (0,1) -> row0 {cols [0,256), [257,513)},
    //                waves (2,3) -> row1. Wave-private x copy, no barriers.
    __shared__ float xs[4][XSZ];

    const int tid  = threadIdx.x;
    const int wid  = tid >> 6;
    const int lane = tid & 63;
    const int row  = blockIdx.x * 2 + (wid >> 1);   // b*C + c
    const int half = wid & 1;
    const int c    = row & (CC - 1);

    const float al = alpha[c];
    const float* xr = x + (size_t)row * LL;
    float* xw = xs[wid];

    // stage x (+ front zeros) into wave-private LDS, swizzled
    for (int k = lane; k < PAD; k += 64) xw[swz(k)] = 0.f;
    for (int k = lane; k < LL;  k += 64) xw[swz(PAD + k)] = xr[k];
    // same-wave DS ops are ordered; no barrier needed.

    const int t0 = half ? (257 + 4 * lane) : (4 * lane);

    // sliding x-window for j=0: (w0..w3) = x[t0-1 .. t0+2]
    float w0 = xw[swz(PAD + t0 - 1)];
    float w1 = xw[swz(PAD + t0)];
    float w2 = xw[swz(PAD + t0 + 1)];
    float w3 = xw[swz(PAD + t0 + 2)];

    f32x4 acc = {0.f, 0.f, 0.f, 0.f};
    float apj = 1.0f;                       // alpha^j
    const float a2 = al * al, a3 = a2 * al, a4 = a2 * a2;

    float* op = out + (size_t)row * (NW * LO) + t0;

#define ROWSTEP(P, A, B, C, D)                                   \
    { f32x4 tv = acc; __builtin_memcpy(op, &tv, 16); op += LO;   \
      acc.x = fmaf((P), (A), acc.x); acc.y = fmaf((P), (B), acc.y); \
      acc.z = fmaf((P), (C), acc.z); acc.w = fmaf((P), (D), acc.w); }
#define ACCSTEP(P, A, B, C, D)                                   \
    { acc.x = fmaf((P), (A), acc.x); acc.y = fmaf((P), (B), acc.y); \
      acc.z = fmaf((P), (C), acc.z); acc.w = fmaf((P), (D), acc.w); }

    // rows 0..47 (store row j, then accumulate step j)
    for (int jb = 0; jb < 48; jb += 4) {
        const int ib = PAD + t0 - 2 - jb;
        const float n1 = xw[swz(ib)];
        const float n2 = xw[swz(ib - 1)];
        const float n3 = xw[swz(ib - 2)];
        const float n4 = xw[swz(ib - 3)];
        const float p1 = apj * al, p2 = apj * a2, p3 = apj * a3;
        ROWSTEP(apj, w0, w1, w2, w3)
        ROWSTEP(p1,  n1, w0, w1, w2)
        ROWSTEP(p2,  n2, n1, w0, w1)
        ROWSTEP(p3,  n3, n2, n1, w0)
        apj *= a4;
        w0 = n4; w1 = n3; w2 = n2; w3 = n1;
    }
    // 16 accumulate-only steps (j=48..63) to reach w=64
    for (int jb = 48; jb < 64; jb += 4) {
        const int ib = PAD + t0 - 2 - jb;
        const float n1 = xw[swz(ib)];
        const float n2 = xw[swz(ib - 1)];
        const float n3 = xw[swz(ib - 2)];
        const float n4 = xw[swz(ib - 3)];
        const float p1 = apj * al, p2 = apj * a2, p3 = apj * a3;
        ACCSTEP(apj, w0, w1, w2, w3)
        ACCSTEP(p1,  n1, w0, w1, w2)
        ACCSTEP(p2,  n2, n1, w0, w1)
        ACCSTEP(p3,  n3, n2, n1, w0)
        apj *= a4;
        w0 = n4; w1 = n3; w2 = n2; w3 = n1;
    }
    { f32x4 tv = acc; __builtin_memcpy(op, &tv, 16); }   // row 48 (w=64)

    // leftover column t=256 (wave half==0): out[j][256] = sum_{k<w_j} a^k x[255-k]
    // via s_k = a^k x[255-k], inclusive shuffle scan; row j <- I_{j-1}.
    if (half == 0) {
        float pl = 1.f, mm = al;                 // pl = alpha^lane
        #pragma unroll
        for (int b = 0; b < 6; ++b) { pl = (lane & (1 << b)) ? pl * mm : pl; mm *= mm; }
        float s = pl * xw[swz(PAD + 255 - lane)];
        #pragma unroll
        for (int off = 1; off < 64; off <<= 1) {
            const float v = __shfl_up(s, off);
            if (lane >= off) s += v;
        }
        float* ocol = out + (size_t)row * (NW * LO) + 256;
        if (lane <= 46) ocol[(size_t)(lane + 1) * LO] = s;   // rows 1..47
        if (lane == 47) ocol[0] = 0.f;                        // row 0 (w=0)
        if (lane == 63) ocol[(size_t)48 * LO] = s;            // row 48 (w=64)
    }
#undef ROWSTEP
#undef ACCSTEP
}

extern "C" void kernel_launch(void* const* d_in, const int* in_sizes, int n_in,
                              void* d_out, int out_size, void* d_ws, size_t ws_size,
                              hipStream_t stream)
{
    const float* x     = (const float*)d_in[0];
    const float* alpha = (const float*)d_in[1];
    float* out = (float*)d_out;

    const int rows = 8 * CC;           // 4096
    const int grid = rows / 2;         // 2 rows per block, all resident
    fofe_kernel<<<grid, 256, 0, stream>>>(x, alpha, out);
}